// Round 4
// baseline (38.879 us; speedup 1.0000x reference)
//
#include <hip/hip_runtime.h>
#include <math.h>

#define LIE_EPS 1e-5f
#define THREADS 256
#define IPT 4
#define ITEMS_PER_BLOCK (THREADS * IPT)   // 1024 items: in 3072 floats, out 9216 floats

typedef float f32x4 __attribute__((ext_vector_type(4)));   // native vec for nontemporal builtins

__device__ __forceinline__ void se2_item(float x, float y, float w, float* o9) {
    float theta_sqr = w * w;
    float theta = fabsf(w);           // sqrt(w*w) == |w|
    float s, c;
    __sincosf(theta, &s, &c);
    float A  = s / (theta + LIE_EPS);
    float Bc = (1.0f - c) / (theta_sqr + LIE_EPS);
    float C  = (1.0f - A) / (theta_sqr + LIE_EPS);
    float r00 = 1.0f - Bc * theta_sqr;       // == r11
    float aw  = A * w;                       // r10 = aw, r01 = -aw
    float v00 = 1.0f - C * theta_sqr;        // == v11
    float bw  = Bc * w;                      // v10 = bw, v01 = -bw
    float tx  = v00 * x - bw * y;
    float ty  = bw * x + v00 * y;
    o9[0] = r00;  o9[1] = -aw;  o9[2] = tx;
    o9[3] = aw;   o9[4] = r00;  o9[5] = ty;
    o9[6] = 0.0f; o9[7] = 0.0f; o9[8] = 1.0f;
}

__global__ __launch_bounds__(THREADS) void lie_se2_kernel(const float* __restrict__ uv,
                                                          float* __restrict__ out,
                                                          int n) {
    __shared__ float sbuf[ITEMS_PER_BLOCK * 9];          // 36 KB output staging
    f32x4* s4 = (f32x4*)sbuf;
    const int tid = threadIdx.x;
    const long long blockItem0 = (long long)blockIdx.x * ITEMS_PER_BLOCK;

    if (blockItem0 + ITEMS_PER_BLOCK <= (long long)n) {
        // ---- direct global loads: 3x float4 per thread, 48 B/lane.
        // Wave covers 64*48 = 3072 contiguous bytes -> full line utilization.
        const f32x4* gin = (const f32x4*)(uv + blockItem0 * 3);
        f32x4 u0 = __builtin_nontemporal_load(&gin[3 * tid + 0]);
        f32x4 u1 = __builtin_nontemporal_load(&gin[3 * tid + 1]);
        f32x4 u2 = __builtin_nontemporal_load(&gin[3 * tid + 2]);
        float in[12] = { u0.x, u0.y, u0.z, u0.w,
                         u1.x, u1.y, u1.z, u1.w,
                         u2.x, u2.y, u2.z, u2.w };

        float o[36];
        #pragma unroll
        for (int m = 0; m < IPT; ++m)
            se2_item(in[3 * m], in[3 * m + 1], in[3 * m + 2], &o[9 * m]);

        // ---- regs->LDS (f4 stride 9 = odd -> conflict-free) ----
        #pragma unroll
        for (int k = 0; k < 9; ++k) {
            f32x4 v = { o[4 * k], o[4 * k + 1], o[4 * k + 2], o[4 * k + 3] };
            s4[9 * tid + k] = v;
        }
        __syncthreads();

        // ---- coalesced LDS->global, nontemporal (streaming, write-once) ----
        f32x4* gout = (f32x4*)(out + blockItem0 * 9);
        #pragma unroll
        for (int k = 0; k < 9; ++k) {
            f32x4 v = s4[tid + THREADS * k];
            __builtin_nontemporal_store(v, &gout[tid + THREADS * k]);
        }
    } else {
        // ---- tail block: scalar, per-item guarded ----
        for (int m = 0; m < IPT; ++m) {
            long long i = blockItem0 + tid + THREADS * m;
            if (i < (long long)n) {
                float x = uv[i * 3 + 0];
                float y = uv[i * 3 + 1];
                float w = uv[i * 3 + 2];
                float o[9];
                se2_item(x, y, w, o);
                #pragma unroll
                for (int k = 0; k < 9; ++k) out[i * 9 + k] = o[k];
            }
        }
    }
}

extern "C" void kernel_launch(void* const* d_in, const int* in_sizes, int n_in,
                              void* d_out, int out_size, void* d_ws, size_t ws_size,
                              hipStream_t stream) {
    const float* uv = (const float*)d_in[0];
    float* out = (float*)d_out;
    int n = in_sizes[0] / 3;   // (B,3)
    int blocks = (n + ITEMS_PER_BLOCK - 1) / ITEMS_PER_BLOCK;
    lie_se2_kernel<<<blocks, THREADS, 0, stream>>>(uv, out, n);
}

// Round 5
// 33.714 us; speedup vs baseline: 1.1532x; 1.1532x over previous
//
#include <hip/hip_runtime.h>
#include <math.h>

#define LIE_EPS 1e-5f
#define THREADS 256
#define IPT 4
#define ITEMS_PER_BLOCK (THREADS * IPT)   // 1024 items: in 3072 floats, out 9216 floats

typedef float f32x4 __attribute__((ext_vector_type(4)));

__device__ __forceinline__ void se2_item(float x, float y, float w, float* o9) {
    float theta_sqr = w * w;
    float theta = fabsf(w);           // sqrt(w*w) == |w|
    float s, c;
    __sincosf(theta, &s, &c);
    float A  = s / (theta + LIE_EPS);
    float Bc = (1.0f - c) / (theta_sqr + LIE_EPS);
    float C  = (1.0f - A) / (theta_sqr + LIE_EPS);
    float r00 = 1.0f - Bc * theta_sqr;       // == r11
    float aw  = A * w;                       // r10 = aw, r01 = -aw
    float v00 = 1.0f - C * theta_sqr;        // == v11
    float bw  = Bc * w;                      // v10 = bw, v01 = -bw
    float tx  = v00 * x - bw * y;
    float ty  = bw * x + v00 * y;
    o9[0] = r00;  o9[1] = -aw;  o9[2] = tx;
    o9[3] = aw;   o9[4] = r00;  o9[5] = ty;
    o9[6] = 0.0f; o9[7] = 0.0f; o9[8] = 1.0f;
}

__global__ __launch_bounds__(THREADS) void lie_se2_kernel(const float* __restrict__ uv,
                                                          float* __restrict__ out,
                                                          int n) {
    __shared__ float sbuf[ITEMS_PER_BLOCK * 9];          // 36 KB output staging
    f32x4* s4 = (f32x4*)sbuf;
    const int tid = threadIdx.x;
    const long long blockItem0 = (long long)blockIdx.x * ITEMS_PER_BLOCK;

    if (blockItem0 + ITEMS_PER_BLOCK <= (long long)n) {
        // ---- direct global loads (plain, cached): 3x float4 per thread, 48 B/lane.
        // A wave's 3 loads together consume 64*48 = 3072 contiguous bytes;
        // L1/L2 hold the partially-used lines between the 3 instructions.
        const f32x4* gin = (const f32x4*)(uv + blockItem0 * 3);
        f32x4 u0 = gin[3 * tid + 0];
        f32x4 u1 = gin[3 * tid + 1];
        f32x4 u2 = gin[3 * tid + 2];
        float in[12] = { u0.x, u0.y, u0.z, u0.w,
                         u1.x, u1.y, u1.z, u1.w,
                         u2.x, u2.y, u2.z, u2.w };

        float o[36];
        #pragma unroll
        for (int m = 0; m < IPT; ++m)
            se2_item(in[3 * m], in[3 * m + 1], in[3 * m + 2], &o[9 * m]);

        // ---- regs->LDS (f4 stride 9 = odd -> conflict-free) ----
        #pragma unroll
        for (int k = 0; k < 9; ++k) {
            f32x4 v = { o[4 * k], o[4 * k + 1], o[4 * k + 2], o[4 * k + 3] };
            s4[9 * tid + k] = v;
        }
        __syncthreads();

        // ---- coalesced LDS->global (lane-contiguous float4) ----
        f32x4* gout = (f32x4*)(out + blockItem0 * 9);
        #pragma unroll
        for (int k = 0; k < 9; ++k)
            gout[tid + THREADS * k] = s4[tid + THREADS * k];
    } else {
        // ---- tail block: scalar, per-item guarded ----
        for (int m = 0; m < IPT; ++m) {
            long long i = blockItem0 + tid + THREADS * m;
            if (i < (long long)n) {
                float x = uv[i * 3 + 0];
                float y = uv[i * 3 + 1];
                float w = uv[i * 3 + 2];
                float o[9];
                se2_item(x, y, w, o);
                #pragma unroll
                for (int k = 0; k < 9; ++k) out[i * 9 + k] = o[k];
            }
        }
    }
}

extern "C" void kernel_launch(void* const* d_in, const int* in_sizes, int n_in,
                              void* d_out, int out_size, void* d_ws, size_t ws_size,
                              hipStream_t stream) {
    const float* uv = (const float*)d_in[0];
    float* out = (float*)d_out;
    int n = in_sizes[0] / 3;   // (B,3)
    int blocks = (n + ITEMS_PER_BLOCK - 1) / ITEMS_PER_BLOCK;
    lie_se2_kernel<<<blocks, THREADS, 0, stream>>>(uv, out, n);
}